// Round 11
// baseline (2404.598 us; speedup 1.0000x reference)
//
#include <hip/hip_runtime.h>
#include <hip/hip_fp8.h>
#include <cstdint>
#include <cstddef>

typedef __bf16 bf16_t;
typedef unsigned char fp8_t;
typedef __attribute__((ext_vector_type(8))) __bf16 bf16x8;
typedef __attribute__((ext_vector_type(4))) float f32x4;

__device__ __forceinline__ void async_cp16(const void* g, void* l) {
    __builtin_amdgcn_global_load_lds(
        (const __attribute__((address_space(1))) void*)g,
        (__attribute__((address_space(3))) void*)l,
        16, 0, 0);
}

__device__ __forceinline__ fp8_t to_fp8(float x) {
    __hip_fp8_e4m3 t(x);
    return t.__x;
}

__device__ __forceinline__ float fast_tanh(float x) {
    float ax = fabsf(x);
    float e = __expf(-2.f * ax);
    float t = (1.f - e) / (1.f + e);
    return x < 0.f ? -t : t;
}
__device__ __forceinline__ float fast_sig(float x) {
    return 1.f / (1.f + __expf(-x));
}

// ---------------- conversion kernels ----------------
__global__ void k_cvt_transpose8(const float* __restrict__ src, fp8_t* __restrict__ dst,
                                 int K, int N) {
    int idx = blockIdx.x * 256 + threadIdx.x;
    if (idx >= K * N) return;
    int k = idx / N, n = idx - k * N;
    dst[(size_t)n * K + k] = to_fp8(src[idx]);
}

__global__ void k_cvt_flat(const float* __restrict__ src, bf16_t* __restrict__ dst, int n) {
    int idx = blockIdx.x * 256 + threadIdx.x;
    if (idx >= n) return;
    dst[idx] = (bf16_t)src[idx];
}

__global__ void k_build_wrz(const float* __restrict__ Wih, const float* __restrict__ Whh,
                            const float* __restrict__ bih, const float* __restrict__ bhh,
                            bf16_t* __restrict__ wrz, float* __restrict__ brz) {
    int idx = blockIdx.x * 256 + threadIdx.x;
    if (idx >= 2048 * 1280) return;
    int n = idx / 1280, c = idx - n * 1280;
    float v = (c < 256) ? Wih[(size_t)n * 256 + c] : Whh[(size_t)n * 1024 + (c - 256)];
    wrz[idx] = (bf16_t)v;
    if (c == 0) brz[n] = bih[n] + bhh[n];
}

__global__ void k_cvt_x(const float* __restrict__ xt, bf16_t* __restrict__ xh, int B) {
    int idx = blockIdx.x * 256 + threadIdx.x;
    if (idx >= B * 256) return;
    int b = idx >> 8, c = idx & 255;
    xh[(size_t)b * 1280 + c] = (bf16_t)xt[idx];
}

__global__ void k_cvt_h0(const float* __restrict__ state, bf16_t* __restrict__ h0b,
                         fp8_t* __restrict__ hs8, int B) {
    int idx = blockIdx.x * 256 + threadIdx.x;
    if (idx >= B * 1024) return;
    int b = idx >> 10, j = idx & 1023;
    float v = state[(size_t)b * 1040 + 16 + j];
    h0b[idx] = (bf16_t)v;
    hs8[idx] = to_fp8(v);
}

enum { EPI_TANH = 0, EPI_RK4 = 1, EPI_SIG = 2, EPI_BIASBF = 3, EPI_FIN = 4 };

// =====================================================================
// fp8 TLP GEMM (RK4 chain): C = A(MxK) * Bt(NxK)^T, e4m3 in, f32 acc.
// 128x128 tile, BK=64, 256 threads (4 waves 2x2; wave = 64x64, acc[4][4]).
// 3-slot LDS (48 KiB -> 3 blocks/CU = 12 waves: TLP latency hiding).
// One barrier + one counted vmcnt(4) per K-iter, depth-2 prefetch.
// Staging is RULE-21 compliant: LDS dest = tid*16 LINEAR (hardware writes
// wave-uniform base + lane*16); the swizzle lives in the GLOBAL source col:
// 16B-slot s of row r holds global col16 s ^ ((r>>1)&3).  (Round 10's NaN
// was a non-linear LDS dest -- DMA scattered the tile.)
// Read: 8B-slot = kg ^ (swr<<1) (kk0) / (4|kg) ^ (swr<<1) (kk1), swr=(fr>>1)&3.
// =====================================================================
template <int EPI, int STAGE>
__global__ __launch_bounds__(256, 4) void gemm128f8(
    const fp8_t* __restrict__ A, int lda,
    const fp8_t* __restrict__ Bt,
    int N, int K,
    const float* __restrict__ bias,
    fp8_t* __restrict__ o8,           // TANH: T8; RK4 0-2: hs8
    const bf16_t* __restrict__ h0b,   // RK4 0-2: h0 (bf16)
    const float* __restrict__ state,  // RK4 3: f32 ld 1040
    bf16_t* __restrict__ kacc,        // RK4: k-sum (bf16)
    bf16_t* __restrict__ xhb)         // RK4 3: = xh + 256 (ld 1280), bf16 ht
{
    __shared__ __align__(16) fp8_t dsA[3][8192];   // 3 slots x 128 rows x 64 k
    __shared__ __align__(16) fp8_t dsB[3][8192];

    const int tid  = threadIdx.x;
    const int lane = tid & 63;
    const int wv   = tid >> 6;

    // XCD-aware bijective swizzle (nwg % 8 == 0 for all grids here)
    const int gx  = gridDim.x;
    int bid = blockIdx.y * gx + blockIdx.x;
    const int nwg = gx * gridDim.y;
    bid = (bid & 7) * (nwg >> 3) + (bid >> 3);
    const int bm = (bid / gx) << 7;
    const int bn = (bid % gx) << 7;

    const int wm = (wv >> 1) << 6;   // 0 or 64
    const int wn = (wv & 1) << 6;    // 0 or 64

    f32x4 acc[4][4] = {};

    // ---- staging: LINEAR LDS dest (tid*16), swizzled global source ----
    const int srow0 = tid >> 2;                 // 0..63 (issue0 row; issue1 = +64)
    const int s4    = tid & 3;                  // 16B slot
    const int swrS  = (srow0 >> 1) & 3;         // same term for row+64 (64/2 % 4 == 0)
    const int scol  = (s4 ^ swrS) << 4;         // swizzled global 16B col
    const fp8_t* gA0 = A  + (size_t)(bm + srow0) * lda + scol;
    const fp8_t* gA1 = gA0 + (size_t)64 * lda;
    const fp8_t* gB0 = Bt + (size_t)(bn + srow0) * K + scol;
    const fp8_t* gB1 = gB0 + (size_t)64 * K;
    const int d0 = tid << 4;                    // linear LDS bytes

    // 4 DMA instrs/thread per K-tile  ->  gate = vmcnt(4)
#define STG(t) do { const int _sl = (t) % 3; const size_t _o = (size_t)(t) << 6; \
        async_cp16(gA0 + _o, (void*)&dsA[_sl][d0]);                              \
        async_cp16(gA1 + _o, (void*)&dsA[_sl][4096 + d0]);                       \
        async_cp16(gB0 + _o, (void*)&dsB[_sl][d0]);                              \
        async_cp16(gB1 + _o, (void*)&dsB[_sl][4096 + d0]); } while (0)

    // ---- fragment offsets (bytes within a slot), swizzled read ----
    const int fr = lane & 15;
    const int kg = lane >> 4;
    const int mS = ((fr >> 1) & 3) << 1;       // swr<<1: even XOR mask on 8B slots
    const int aRow = (wm + fr) * 64;
    const int bRow = (wn + fr) * 64;
    const int sk0 = ((kg ^ mS) & 7) << 3;        // kk = 0
    const int sk1 = (((4 | kg) ^ mS) & 7) << 3;  // kk = 1

    const int NT = K >> 6;

    STG(0);
    STG(1);

    for (int kt = 0; kt < NT; ++kt) {
        if (kt + 1 < NT) asm volatile("s_waitcnt vmcnt(4)" ::: "memory");
        else             asm volatile("s_waitcnt vmcnt(0)" ::: "memory");
        __builtin_amdgcn_s_barrier();

        if (kt + 2 < NT) STG(kt + 2);

        const fp8_t* as = dsA[kt % 3];
        const fp8_t* bs = dsB[kt % 3];
        long a0[4], a1[4], b0[4], b1[4];
#pragma unroll
        for (int i = 0; i < 4; ++i) {
            a0[i] = *(const long*)(as + aRow + i * 1024 + sk0);
            a1[i] = *(const long*)(as + aRow + i * 1024 + sk1);
        }
#pragma unroll
        for (int j = 0; j < 4; ++j) {
            b0[j] = *(const long*)(bs + bRow + j * 1024 + sk0);
            b1[j] = *(const long*)(bs + bRow + j * 1024 + sk1);
        }

        __builtin_amdgcn_s_setprio(1);
#pragma unroll
        for (int i = 0; i < 4; ++i)
#pragma unroll
            for (int j = 0; j < 4; ++j)
                acc[i][j] = __builtin_amdgcn_mfma_f32_16x16x32_fp8_fp8(
                    a0[i], b0[j], acc[i][j], 0, 0, 0);
#pragma unroll
        for (int i = 0; i < 4; ++i)
#pragma unroll
            for (int j = 0; j < 4; ++j)
                acc[i][j] = __builtin_amdgcn_mfma_f32_16x16x32_fp8_fp8(
                    a1[i], b1[j], acc[i][j], 0, 0, 0);
        __builtin_amdgcn_s_setprio(0);
    }
#undef STG

    // C/D layout: col = lane&15, row = (lane>>4)*4 + reg
    const int orow0 = bm + wm + (kg << 2);
    const int ocol0 = bn + wn + fr;
#pragma unroll
    for (int i = 0; i < 4; ++i) {
#pragma unroll
        for (int j = 0; j < 4; ++j) {
#pragma unroll
            for (int r = 0; r < 4; ++r) {
                const int row = orow0 + i * 16 + r;
                const int col = ocol0 + j * 16;
                const float c = acc[i][j][r];
                if constexpr (EPI == EPI_TANH) {
                    o8[(size_t)row * N + col] = to_fp8(fast_tanh(c + bias[col]));
                } else {  // EPI_RK4
                    const float kk = c + bias[col];
                    const size_t hidx = ((size_t)row << 10) + col;
                    if constexpr (STAGE == 0) {
                        const float h0 = (float)h0b[hidx];
                        kacc[hidx] = (bf16_t)kk;
                        o8[hidx] = to_fp8(h0 + 0.05f * kk);
                    } else if constexpr (STAGE == 1) {
                        const float h0 = (float)h0b[hidx];
                        kacc[hidx] = (bf16_t)((float)kacc[hidx] + 2.f * kk);
                        o8[hidx] = to_fp8(h0 + 0.05f * kk);
                    } else if constexpr (STAGE == 2) {
                        const float h0 = (float)h0b[hidx];
                        kacc[hidx] = (bf16_t)((float)kacc[hidx] + 2.f * kk);
                        o8[hidx] = to_fp8(h0 + 0.1f * kk);
                    } else {
                        const float h0 = state[(size_t)row * 1040 + 16 + col];
                        const float ht = h0 + (0.1f / 6.f) * ((float)kacc[hidx] + kk);
                        xhb[(size_t)row * 1280 + col] = (bf16_t)ht;   // bf16 only
                    }
                }
            }
        }
    }
}

// =====================================================================
// bf16 GEMM (GRU): 8-phase, 256x256, BK=64, 512 threads, LDS 128 KiB.
// vmcnt(6) gates.  Slot-XOR swizzle s4 ^= (row>>1)&3 (0 conflicts).
// FIN reads ht from its own (L2-hot) A operand (xh bf16).
// =====================================================================
template <int EPI>
__global__ __launch_bounds__(512, 2) void gemm256bf(
    const bf16_t* __restrict__ A, int lda,
    const bf16_t* __restrict__ Bt,
    int N, int K,
    const float* __restrict__ bias,
    bf16_t* __restrict__ o16,         // SIG: rz; BIASBF: inb
    const bf16_t* __restrict__ rz,    // FIN
    const bf16_t* __restrict__ inb,   // FIN
    float* __restrict__ outp)         // FIN: f32 out ld 1040
{
    __shared__ __align__(16) bf16_t dsA[32768];
    __shared__ __align__(16) bf16_t dsB[32768];

    const int tid  = threadIdx.x;
    const int lane = tid & 63;
    const int wv   = tid >> 6;

    const int gx  = gridDim.x;
    int bid = blockIdx.y * gx + blockIdx.x;
    const int nwg = gx * gridDim.y;
    if ((nwg & 7) == 0) bid = (bid & 7) * (nwg >> 3) + (bid >> 3);
    const int bm = (bid / gx) << 8;
    const int bn = (bid % gx) << 8;

    const int wm = (wv >> 2) << 7;
    const int wn = (wv & 3) << 6;

    f32x4 acc[8][4] = {};

    const int srow  = tid >> 2;
    const int sslot = tid & 3;
    const int ssw   = (sslot ^ ((srow >> 1) & 3)) << 3;
    const bf16_t* gA_s = A  + (size_t)(bm + srow) * lda + ssw;
    const bf16_t* gB_s = Bt + (size_t)(bn + srow) * K + ssw;
    const size_t a128 = (size_t)128 * lda;
    const size_t b128 = (size_t)128 * K;
    const int dst0 = srow * 32 + sslot * 8;   // elems = tid*16 bytes (linear)

#define STG_A(t, kkv) do {                                                     \
        const int _pl = ((t) & 1) * 16384 + (kkv) * 8192;                      \
        const size_t _go = (size_t)(t) * 64 + (kkv) * 32;                      \
        async_cp16(gA_s + _go,        (void*)&dsA[_pl + dst0]);                \
        async_cp16(gA_s + a128 + _go, (void*)&dsA[_pl + dst0 + 4096]);         \
    } while (0)
#define STG_B(t, kkv) do {                                                     \
        const int _pl = ((t) & 1) * 16384 + (kkv) * 8192;                      \
        const size_t _go = (size_t)(t) * 64 + (kkv) * 32;                      \
        async_cp16(gB_s + _go,        (void*)&dsB[_pl + dst0]);                \
        async_cp16(gB_s + b128 + _go, (void*)&dsB[_pl + dst0 + 4096]);         \
    } while (0)

    const int fr   = lane & 15;
    const int kg   = lane >> 4;
    const int frsw = (fr >> 1) & 3;
    const int aBase = (wm + fr) * 32 + ((kg ^ frsw) << 3);
    const int bBase = (wn + fr) * 32 + ((kg ^ frsw) << 3);

#define DS_A(dst, ih, kkv, bufv) do {                                          \
        const bf16_t* _p = &dsA[(bufv) * 16384 + (kkv) * 8192 + aBase + (ih) * 2048]; \
        dst[0] = *(const bf16x8*)(_p);                                         \
        dst[1] = *(const bf16x8*)(_p + 512);                                   \
        dst[2] = *(const bf16x8*)(_p + 1024);                                  \
        dst[3] = *(const bf16x8*)(_p + 1536);                                  \
    } while (0)
#define DS_B(dst, kkv, bufv) do {                                              \
        const bf16_t* _p = &dsB[(bufv) * 16384 + (kkv) * 8192 + bBase];        \
        dst[0] = *(const bf16x8*)(_p);                                         \
        dst[1] = *(const bf16x8*)(_p + 512);                                   \
        dst[2] = *(const bf16x8*)(_p + 1024);                                  \
        dst[3] = *(const bf16x8*)(_p + 1536);                                  \
    } while (0)

#define MFMA_Q(am, ib) do {                                                    \
        __builtin_amdgcn_s_setprio(1);                                         \
        _Pragma("unroll")                                                      \
        for (int x = 0; x < 4; ++x)                                            \
        _Pragma("unroll")                                                      \
        for (int j = 0; j < 4; ++j)                                            \
            acc[(ib) + x][j] = __builtin_amdgcn_mfma_f32_16x16x32_bf16(        \
                am[x], bF[j], acc[(ib) + x][j], 0, 0, 0);                      \
        __builtin_amdgcn_s_setprio(0);                                         \
    } while (0)

#define BAR()  __builtin_amdgcn_s_barrier()
#define LG0()  do { asm volatile("s_waitcnt lgkmcnt(0)" ::: "memory");         \
                    __builtin_amdgcn_sched_barrier(0); } while (0)

    const int NT = K >> 6;
    const int NI = NT >> 1;

    bf16x8 aL[4], aH[4], bF[4];

    STG_A(0, 0); STG_B(0, 0); STG_A(0, 1); STG_B(0, 1);
    STG_A(1, 0); STG_B(1, 0); STG_A(1, 1); STG_B(1, 1);
    asm volatile("s_waitcnt vmcnt(8)" ::: "memory");
    BAR();

    for (int s = 0; s < NI; ++s) {
        const int t1 = 2 * s + 1;
        const int ta = 2 * s + 2;
        const int tb = 2 * s + 3;
        const bool more = (s + 1 < NI);

        DS_A(aL, 0, 0, 0); DS_B(bF, 0, 0);
        if (s > 0) STG_A(t1, 1);
        BAR(); LG0(); MFMA_Q(aL, 0); BAR();

        DS_A(aH, 1, 0, 0);
        if (more) STG_B(ta, 0);
        BAR(); LG0(); MFMA_Q(aH, 4); BAR();

        DS_A(aL, 0, 1, 0); DS_B(bF, 1, 0);
        if (more) STG_A(ta, 0);
        BAR(); LG0(); MFMA_Q(aL, 0); BAR();

        DS_A(aH, 1, 1, 0);
        if (more) STG_B(ta, 1);
        BAR(); LG0(); MFMA_Q(aH, 4);
        if (more) asm volatile("s_waitcnt vmcnt(6)" ::: "memory");
        else      asm volatile("s_waitcnt vmcnt(0)" ::: "memory");
        BAR();

        DS_A(aL, 0, 0, 1); DS_B(bF, 0, 1);
        if (more) STG_A(ta, 1);
        BAR(); LG0(); MFMA_Q(aL, 0); BAR();

        DS_A(aH, 1, 0, 1);
        if (more) STG_B(tb, 0);
        BAR(); LG0(); MFMA_Q(aH, 4); BAR();

        DS_A(aL, 0, 1, 1); DS_B(bF, 1, 1);
        if (more) STG_A(tb, 0);
        BAR(); LG0(); MFMA_Q(aL, 0); BAR();

        DS_A(aH, 1, 1, 1);
        if (more) STG_B(tb, 1);
        BAR(); LG0(); MFMA_Q(aH, 4);
        if (more) asm volatile("s_waitcnt vmcnt(6)" ::: "memory");
        else      asm volatile("s_waitcnt vmcnt(0)" ::: "memory");
        BAR();
    }
#undef STG_A
#undef STG_B
#undef DS_A
#undef DS_B
#undef MFMA_Q
#undef BAR
#undef LG0

    const int orow0 = bm + wm + (kg << 2);
    const int ocol0 = bn + wn + fr;
#pragma unroll
    for (int i = 0; i < 8; ++i) {
#pragma unroll
        for (int j = 0; j < 4; ++j) {
#pragma unroll
            for (int r = 0; r < 4; ++r) {
                const int row = orow0 + i * 16 + r;
                const int col = ocol0 + j * 16;
                const float c = acc[i][j][r];
                if constexpr (EPI == EPI_SIG) {
                    o16[(size_t)row * N + col] = (bf16_t)fast_sig(c + bias[col]);
                } else if constexpr (EPI == EPI_BIASBF) {
                    o16[(size_t)row * N + col] = (bf16_t)(c + bias[col]);
                } else {  // EPI_FIN
                    const float hn  = c + bias[col];
                    const float r_  = (float)rz[((size_t)row << 11) + col];
                    const float z_  = (float)rz[((size_t)row << 11) + 1024 + col];
                    const float inv = (float)inb[((size_t)row << 10) + col];
                    const float nn  = fast_tanh(inv + r_ * hn);
                    const float htv = (float)A[(size_t)row * lda + col];  // ht, L2-hot
                    outp[(size_t)row * 1040 + 16 + col] = (1.f - z_) * nn + z_ * htv;
                }
            }
        }
    }
}

// ---------------- readout: out[:, :16] ----------------
__global__ void k_ly(const float* __restrict__ outh, const float* __restrict__ state,
                     const float* __restrict__ Wly, const float* __restrict__ bly,
                     const int* __restrict__ y_type, float* __restrict__ outp, int B) {
    int t = blockIdx.x * 256 + threadIdx.x;
    if (t >= B * 16) return;
    int o = t & 15, b = t >> 4;
    const float4* hrow = (const float4*)(outh + (size_t)b * 1040 + 16);
    float s = bly[o];
#pragma unroll 4
    for (int k4 = 0; k4 < 256; ++k4) {
        float4 h = hrow[k4];
        int k = k4 << 2;
        s += h.x * Wly[(k + 0) * 16 + o] + h.y * Wly[(k + 1) * 16 + o]
           + h.z * Wly[(k + 2) * 16 + o] + h.w * Wly[(k + 3) * 16 + o];
    }
    outp[(size_t)b * 1040 + o] = (y_type[o] == 0) ? s : state[(size_t)b * 1040 + o];
}

// ---------------- launcher ----------------
extern "C" void kernel_launch(void* const* d_in, const int* in_sizes, int n_in,
                              void* d_out, int out_size, void* d_ws, size_t ws_size,
                              hipStream_t stream) {
    const float* state = (const float*)d_in[0];
    const float* xt    = (const float*)d_in[1];
    const float* W1    = (const float*)d_in[2];
    const float* b1    = (const float*)d_in[3];
    const float* W2    = (const float*)d_in[4];
    const float* b2    = (const float*)d_in[5];
    const float* Wih   = (const float*)d_in[6];
    const float* Whh   = (const float*)d_in[7];
    const float* bih   = (const float*)d_in[8];
    const float* bhh   = (const float*)d_in[9];
    const float* Wly   = (const float*)d_in[10];
    const float* bly   = (const float*)d_in[11];
    const int*   y_type = (const int*)d_in[12];
    float* out = (float*)d_out;

    const int B = in_sizes[0] / 1040;   // 32768

    char* ws = (char*)d_ws;
    fp8_t*  w1t8 = (fp8_t*) (ws);                    // 2048 x 1024 fp8
    fp8_t*  w2t8 = (fp8_t*) (ws + 2097152);          // 1024 x 2048 fp8
    bf16_t* wrz  = (bf16_t*)(ws + 4194304);          // 2048 x 1280 bf16
    bf16_t* win  = (bf16_t*)(ws + 9437184);          // 1024 x 256 bf16
    bf16_t* whn  = (bf16_t*)(ws + 9961472);          // 1024 x 1024 bf16
    float*  brz  = (float*) (ws + 12058624);         // 2048
    bf16_t* xh   = (bf16_t*)(ws + 12066816);         // B x 1280 bf16 [x|ht]
    fp8_t*  hs8  = (fp8_t*) (ws + 95952896);         // B x 1024 fp8 stage-h
    bf16_t* kacc = (bf16_t*)(ws + 129507328);        // B x 1024 bf16 k-sum
    fp8_t*  T8   = (fp8_t*) (ws + 196616192);        // B x 2048 fp8 tanh
    bf16_t* h0b  = (bf16_t*)(ws + 263725056);        // B x 1024 bf16 h0
    // overlays (after RK4 completes):
    bf16_t* rz   = (bf16_t*)(ws + 196616192);        // B x 2048 bf16 (over T8+h0b)
    bf16_t* inb  = (bf16_t*)(ws + 95952896);         // B x 1024 bf16 (over hs8+kacc)

    // weight prep + input casts
    k_cvt_transpose8<<<(1024 * 2048) / 256, 256, 0, stream>>>(W1, w1t8, 1024, 2048);
    k_cvt_transpose8<<<(2048 * 1024) / 256, 256, 0, stream>>>(W2, w2t8, 2048, 1024);
    k_build_wrz<<<(2048 * 1280) / 256, 256, 0, stream>>>(Wih, Whh, bih, bhh, wrz, brz);
    k_cvt_flat<<<(1024 * 256) / 256, 256, 0, stream>>>(Wih + 2048 * 256, win, 1024 * 256);
    k_cvt_flat<<<(1024 * 1024) / 256, 256, 0, stream>>>(Whh + 2048 * 1024, whn, 1024 * 1024);
    k_cvt_x<<<(B * 256) / 256, 256, 0, stream>>>(xt, xh, B);
    k_cvt_h0<<<(B * 1024) / 256, 256, 0, stream>>>(state, h0b, hs8, B);

    const int MB128 = B / 128;   // 256 m-tiles (fp8 kernel)
    const int MB256 = B / 256;   // 128 m-tiles (bf16 kernel)

    // ---- RK4 (fp8 TLP GEMMs) ----
    gemm128f8<EPI_TANH, 0><<<dim3(16, MB128), 256, 0, stream>>>(hs8, 1024, w1t8, 2048, 1024,
        b1, T8, nullptr, nullptr, nullptr, nullptr);
    gemm128f8<EPI_RK4, 0><<<dim3(8, MB128), 256, 0, stream>>>(T8, 2048, w2t8, 1024, 2048,
        b2, hs8, h0b, nullptr, kacc, nullptr);

    gemm128f8<EPI_TANH, 0><<<dim3(16, MB128), 256, 0, stream>>>(hs8, 1024, w1t8, 2048, 1024,
        b1, T8, nullptr, nullptr, nullptr, nullptr);
    gemm128f8<EPI_RK4, 1><<<dim3(8, MB128), 256, 0, stream>>>(T8, 2048, w2t8, 1024, 2048,
        b2, hs8, h0b, nullptr, kacc, nullptr);

    gemm128f8<EPI_TANH, 0><<<dim3(16, MB128), 256, 0, stream>>>(hs8, 1024, w1t8, 2048, 1024,
        b1, T8, nullptr, nullptr, nullptr, nullptr);
    gemm128f8<EPI_RK4, 2><<<dim3(8, MB128), 256, 0, stream>>>(T8, 2048, w2t8, 1024, 2048,
        b2, hs8, h0b, nullptr, kacc, nullptr);

    gemm128f8<EPI_TANH, 0><<<dim3(16, MB128), 256, 0, stream>>>(hs8, 1024, w1t8, 2048, 1024,
        b1, T8, nullptr, nullptr, nullptr, nullptr);
    gemm128f8<EPI_RK4, 3><<<dim3(8, MB128), 256, 0, stream>>>(T8, 2048, w2t8, 1024, 2048,
        b2, nullptr, nullptr, state, kacc, xh + 256);

    // ---- GRU (bf16 8-phase GEMMs) ----
    gemm256bf<EPI_SIG><<<dim3(8, MB256), 512, 0, stream>>>(xh, 1280, wrz, 2048, 1280,
        brz, rz, nullptr, nullptr, nullptr);
    gemm256bf<EPI_BIASBF><<<dim3(4, MB256), 512, 0, stream>>>(xh, 1280, win, 1024, 256,
        bih + 2048, inb, nullptr, nullptr, nullptr);
    gemm256bf<EPI_FIN><<<dim3(4, MB256), 512, 0, stream>>>(xh + 256, 1280, whn, 1024, 1024,
        bhh + 2048, nullptr, rz, inb, out);

    // ---- readout out[:, :16] ----
    k_ly<<<(B * 16) / 256, 256, 0, stream>>>(out, state, Wly, bly, y_type, out, B);
}

// Round 12
// 1849.126 us; speedup vs baseline: 1.3004x; 1.3004x over previous
//
#include <hip/hip_runtime.h>
#include <hip/hip_fp8.h>
#include <cstdint>
#include <cstddef>

typedef __bf16 bf16_t;
typedef unsigned char fp8_t;
typedef __attribute__((ext_vector_type(8))) __bf16 bf16x8;
typedef __attribute__((ext_vector_type(4))) float f32x4;

__device__ __forceinline__ void async_cp16(const void* g, void* l) {
    __builtin_amdgcn_global_load_lds(
        (const __attribute__((address_space(1))) void*)g,
        (__attribute__((address_space(3))) void*)l,
        16, 0, 0);
}

__device__ __forceinline__ fp8_t to_fp8(float x) {
    __hip_fp8_e4m3 t(x);
    return t.__x;
}

__device__ __forceinline__ float fast_tanh(float x) {
    float ax = fabsf(x);
    float e = __expf(-2.f * ax);
    float t = (1.f - e) / (1.f + e);
    return x < 0.f ? -t : t;
}
__device__ __forceinline__ float fast_sig(float x) {
    return 1.f / (1.f + __expf(-x));
}

// ---------------- conversion kernels ----------------
__global__ void k_cvt_transpose8(const float* __restrict__ src, fp8_t* __restrict__ dst,
                                 int K, int N) {
    int idx = blockIdx.x * 256 + threadIdx.x;
    if (idx >= K * N) return;
    int k = idx / N, n = idx - k * N;
    dst[(size_t)n * K + k] = to_fp8(src[idx]);
}

__global__ void k_cvt_flat(const float* __restrict__ src, bf16_t* __restrict__ dst, int n) {
    int idx = blockIdx.x * 256 + threadIdx.x;
    if (idx >= n) return;
    dst[idx] = (bf16_t)src[idx];
}

__global__ void k_build_wrz(const float* __restrict__ Wih, const float* __restrict__ Whh,
                            const float* __restrict__ bih, const float* __restrict__ bhh,
                            bf16_t* __restrict__ wrz, float* __restrict__ brz) {
    int idx = blockIdx.x * 256 + threadIdx.x;
    if (idx >= 2048 * 1280) return;
    int n = idx / 1280, c = idx - n * 1280;
    float v = (c < 256) ? Wih[(size_t)n * 256 + c] : Whh[(size_t)n * 1024 + (c - 256)];
    wrz[idx] = (bf16_t)v;
    if (c == 0) brz[n] = bih[n] + bhh[n];
}

__global__ void k_cvt_x(const float* __restrict__ xt, bf16_t* __restrict__ xh, int B) {
    int idx = blockIdx.x * 256 + threadIdx.x;
    if (idx >= B * 256) return;
    int b = idx >> 8, c = idx & 255;
    xh[(size_t)b * 1280 + c] = (bf16_t)xt[idx];
}

__global__ void k_cvt_h0(const float* __restrict__ state, bf16_t* __restrict__ h0b,
                         fp8_t* __restrict__ hs8, int B) {
    int idx = blockIdx.x * 256 + threadIdx.x;
    if (idx >= B * 1024) return;
    int b = idx >> 10, j = idx & 1023;
    float v = state[(size_t)b * 1040 + 16 + j];
    h0b[idx] = (bf16_t)v;
    hs8[idx] = to_fp8(v);
}

enum { EPI_TANH = 0, EPI_RK4 = 1, EPI_SIG = 2, EPI_BIASBF = 3, EPI_FIN = 4 };

// =====================================================================
// fp8 GEMM (RK4 chain): round-4 geometry with BK=64 -> half the barrier
// windows, 32 MFMA/wave per window.  128x256 tile, 512 threads (8 waves
// 2M x 4N; wave = 64x64, acc[4][4]).  3-slot LDS (72 KiB -> ~2 blocks/CU
// TLP).  One counted vmcnt(3) + one raw barrier per K-iter, depth-2
// prefetch.  Staging rule-21 compliant: LDS dest = tid*16 LINEAR; swizzle
// on GLOBAL source col16 (s4 ^ ((row>>1)&3)); read slots verified:
// kk0: (kg ^ 2swr)*8, kk1: ((4|kg) ^ 2swr)*8, swr=(fr>>1)&3.
// =====================================================================
template <int EPI, int STAGE>
__global__ __launch_bounds__(512, 4) void gemm128f8(
    const fp8_t* __restrict__ A, int lda,
    const fp8_t* __restrict__ Bt,
    int N, int K,
    const float* __restrict__ bias,
    fp8_t* __restrict__ o8,           // TANH: T8; RK4 0-2: hs8
    const bf16_t* __restrict__ h0b,   // RK4 0-2: h0 (bf16)
    const float* __restrict__ state,  // RK4 3: f32 ld 1040
    bf16_t* __restrict__ kacc,        // RK4: k-sum (bf16)
    bf16_t* __restrict__ xhb)         // RK4 3: = xh + 256 (ld 1280), bf16 ht
{
    __shared__ __align__(16) fp8_t dsA[3][8192];    // 3 x (128 rows x 64 k)
    __shared__ __align__(16) fp8_t dsB[3][16384];   // 3 x (256 rows x 64 k)

    const int tid  = threadIdx.x;
    const int lane = tid & 63;
    const int wv   = tid >> 6;

    // XCD-aware bijective swizzle (nwg % 8 == 0 for all grids here)
    const int gx  = gridDim.x;
    int bid = blockIdx.y * gx + blockIdx.x;
    const int nwg = gx * gridDim.y;
    bid = (bid & 7) * (nwg >> 3) + (bid >> 3);
    const int bm = (bid / gx) << 7;   // 128-row tiles
    const int bn = (bid % gx) << 8;   // 256-col tiles

    const int wm = (wv >> 2) << 6;    // 0 or 64
    const int wn = (wv & 3) << 6;     // 0,64,128,192

    f32x4 acc[4][4] = {};

    // ---- staging: LINEAR LDS dest (tid*16), swizzled global source ----
    const int srow = tid >> 2;                        // 0..127
    const int s4   = tid & 3;                         // 16B slot
    const int scol = ((s4 ^ ((srow >> 1) & 3)) << 4); // swizzled global col (bytes)
    const fp8_t* gA0 = A  + (size_t)(bm + srow) * lda + scol;
    const fp8_t* gB0 = Bt + (size_t)(bn + srow) * K + scol;
    const fp8_t* gB1 = gB0 + (size_t)128 * K;         // rows+128: swizzle invariant
    const int d0 = tid << 4;                          // linear LDS bytes

    // 3 DMA instrs/thread per K-tile  ->  gate = vmcnt(3)
#define STG(t) do { const int _sl = (t) % 3; const size_t _o = (size_t)(t) << 6; \
        async_cp16(gA0 + _o, (void*)&dsA[_sl][d0]);                              \
        async_cp16(gB0 + _o, (void*)&dsB[_sl][d0]);                              \
        async_cp16(gB1 + _o, (void*)&dsB[_sl][8192 + d0]); } while (0)

    // ---- fragment offsets (bytes within a slot), swizzled read ----
    const int fr  = lane & 15;
    const int kg  = lane >> 4;
    const int mS  = ((fr >> 1) & 3) << 1;             // 2*swr
    const int aRow = (wm + fr) * 64;
    const int bRow = (wn + fr) * 64;
    const int sk0 = ((kg ^ mS) & 7) << 3;             // kk = 0
    const int sk1 = (((4 | kg) ^ mS) & 7) << 3;       // kk = 1

    const int NT = K >> 6;

    STG(0);
    STG(1);

    for (int kt = 0; kt < NT; ++kt) {
        if (kt + 1 < NT) asm volatile("s_waitcnt vmcnt(3)" ::: "memory");
        else             asm volatile("s_waitcnt vmcnt(0)" ::: "memory");
        __builtin_amdgcn_s_barrier();

        if (kt + 2 < NT) STG(kt + 2);

        const fp8_t* as = dsA[kt % 3];
        const fp8_t* bs = dsB[kt % 3];
        long a0[4], a1[4], b0[4], b1[4];
#pragma unroll
        for (int i = 0; i < 4; ++i) {
            a0[i] = *(const long*)(as + aRow + i * 1024 + sk0);
            a1[i] = *(const long*)(as + aRow + i * 1024 + sk1);
        }
#pragma unroll
        for (int j = 0; j < 4; ++j) {
            b0[j] = *(const long*)(bs + bRow + j * 1024 + sk0);
            b1[j] = *(const long*)(bs + bRow + j * 1024 + sk1);
        }

        __builtin_amdgcn_s_setprio(1);
#pragma unroll
        for (int i = 0; i < 4; ++i)
#pragma unroll
            for (int j = 0; j < 4; ++j)
                acc[i][j] = __builtin_amdgcn_mfma_f32_16x16x32_fp8_fp8(
                    a0[i], b0[j], acc[i][j], 0, 0, 0);
#pragma unroll
        for (int i = 0; i < 4; ++i)
#pragma unroll
            for (int j = 0; j < 4; ++j)
                acc[i][j] = __builtin_amdgcn_mfma_f32_16x16x32_fp8_fp8(
                    a1[i], b1[j], acc[i][j], 0, 0, 0);
        __builtin_amdgcn_s_setprio(0);
    }
#undef STG

    // C/D layout: col = lane&15, row = (lane>>4)*4 + reg
    const int orow0 = bm + wm + (kg << 2);
    const int ocol0 = bn + wn + fr;
#pragma unroll
    for (int i = 0; i < 4; ++i) {
#pragma unroll
        for (int j = 0; j < 4; ++j) {
#pragma unroll
            for (int r = 0; r < 4; ++r) {
                const int row = orow0 + i * 16 + r;
                const int col = ocol0 + j * 16;
                const float c = acc[i][j][r];
                if constexpr (EPI == EPI_TANH) {
                    o8[(size_t)row * N + col] = to_fp8(fast_tanh(c + bias[col]));
                } else {  // EPI_RK4
                    const float kk = c + bias[col];
                    const size_t hidx = ((size_t)row << 10) + col;
                    if constexpr (STAGE == 0) {
                        const float h0 = (float)h0b[hidx];
                        kacc[hidx] = (bf16_t)kk;
                        o8[hidx] = to_fp8(h0 + 0.05f * kk);
                    } else if constexpr (STAGE == 1) {
                        const float h0 = (float)h0b[hidx];
                        kacc[hidx] = (bf16_t)((float)kacc[hidx] + 2.f * kk);
                        o8[hidx] = to_fp8(h0 + 0.05f * kk);
                    } else if constexpr (STAGE == 2) {
                        const float h0 = (float)h0b[hidx];
                        kacc[hidx] = (bf16_t)((float)kacc[hidx] + 2.f * kk);
                        o8[hidx] = to_fp8(h0 + 0.1f * kk);
                    } else {
                        const float h0 = state[(size_t)row * 1040 + 16 + col];
                        const float ht = h0 + (0.1f / 6.f) * ((float)kacc[hidx] + kk);
                        xhb[(size_t)row * 1280 + col] = (bf16_t)ht;
                    }
                }
            }
        }
    }
}

// =====================================================================
// bf16 GEMM (GRU): round-4 proven structure.  128x256 tile, BK=32,
// 512 threads (8 waves 2x4; wave = 64x64, acc[4][4]), 3-slot LDS 72 KiB,
// one vmcnt(3) + one barrier per K-iter, depth-2 prefetch, slot-XOR
// swizzle (0 conflicts verified).  FIN reads ht from its A operand.
// =====================================================================
template <int EPI>
__global__ __launch_bounds__(512, 4) void gemm128bf(
    const bf16_t* __restrict__ A, int lda,
    const bf16_t* __restrict__ Bt,
    int N, int K,
    const float* __restrict__ bias,
    bf16_t* __restrict__ o16,         // SIG: rz; BIASBF: inb
    const bf16_t* __restrict__ rz,    // FIN
    const bf16_t* __restrict__ inb,   // FIN
    float* __restrict__ outp)         // FIN: f32 out ld 1040
{
    __shared__ __align__(16) bf16_t As[3][4096];   // 3 x (128 rows x 32 k)
    __shared__ __align__(16) bf16_t Bs[3][8192];   // 3 x (256 rows x 32 k)

    const int tid  = threadIdx.x;
    const int lane = tid & 63;
    const int wv   = tid >> 6;

    const int gx  = gridDim.x;
    int bid = blockIdx.y * gx + blockIdx.x;
    const int nwg = gx * gridDim.y;
    if ((nwg & 7) == 0) bid = (bid & 7) * (nwg >> 3) + (bid >> 3);
    const int bm = (bid / gx) << 7;
    const int bn = (bid % gx) << 8;

    const int wm = (wv >> 2) << 6;
    const int wn = (wv & 3) << 6;

    f32x4 acc[4][4] = {};

    const int srow = tid >> 2;                        // 0..127
    const int s4   = tid & 3;
    const int scw  = (s4 ^ ((srow >> 1) & 3)) << 3;   // swizzled col (elems)
    const bf16_t* gA0 = A  + (size_t)(bm + srow) * lda + scw;
    const bf16_t* gB0 = Bt + (size_t)(bn + srow) * K + scw;
    const bf16_t* gB1 = gB0 + (size_t)128 * K;
    const int ldsOff = tid << 3;                      // elems (16B/thread)

#define STG(t) do { const int _sl = (t) % 3; const size_t _o = (size_t)(t) << 5; \
        async_cp16(gA0 + _o, (void*)&As[_sl][ldsOff]);                           \
        async_cp16(gB0 + _o, (void*)&Bs[_sl][ldsOff]);                           \
        async_cp16(gB1 + _o, (void*)&Bs[_sl][4096 + ldsOff]); } while (0)

    const int fr = lane & 15;
    const int kg = lane >> 4;
    const int ra = wm + fr;
    const int rb = wn + fr;
    const int aoff0 = ra * 32 + ((kg ^ ((ra >> 1) & 3)) << 3);
    const int boff0 = rb * 32 + ((kg ^ ((rb >> 1) & 3)) << 3);

    const int NT = K >> 5;

    STG(0);
    STG(1);

    for (int kt = 0; kt < NT; ++kt) {
        if (kt + 1 < NT) asm volatile("s_waitcnt vmcnt(3)" ::: "memory");
        else             asm volatile("s_waitcnt vmcnt(0)" ::: "memory");
        __builtin_amdgcn_s_barrier();

        if (kt + 2 < NT) STG(kt + 2);

        const bf16_t* as = &As[kt % 3][0];
        const bf16_t* bs = &Bs[kt % 3][0];
        bf16x8 af[4], bfr[4];
#pragma unroll
        for (int i = 0; i < 4; ++i) af[i]  = *(const bf16x8*)(as + aoff0 + i * 512);
#pragma unroll
        for (int j = 0; j < 4; ++j) bfr[j] = *(const bf16x8*)(bs + boff0 + j * 512);

        __builtin_amdgcn_s_setprio(1);
#pragma unroll
        for (int i = 0; i < 4; ++i)
#pragma unroll
            for (int j = 0; j < 4; ++j)
                acc[i][j] = __builtin_amdgcn_mfma_f32_16x16x32_bf16(af[i], bfr[j], acc[i][j], 0, 0, 0);
        __builtin_amdgcn_s_setprio(0);
    }
#undef STG

    const int orow0 = bm + wm + (kg << 2);
    const int ocol0 = bn + wn + fr;
#pragma unroll
    for (int i = 0; i < 4; ++i) {
#pragma unroll
        for (int j = 0; j < 4; ++j) {
#pragma unroll
            for (int r = 0; r < 4; ++r) {
                const int row = orow0 + i * 16 + r;
                const int col = ocol0 + j * 16;
                const float c = acc[i][j][r];
                if constexpr (EPI == EPI_SIG) {
                    o16[(size_t)row * N + col] = (bf16_t)fast_sig(c + bias[col]);
                } else if constexpr (EPI == EPI_BIASBF) {
                    o16[(size_t)row * N + col] = (bf16_t)(c + bias[col]);
                } else {  // EPI_FIN
                    const float hn  = c + bias[col];
                    const float r_  = (float)rz[((size_t)row << 11) + col];
                    const float z_  = (float)rz[((size_t)row << 11) + 1024 + col];
                    const float inv = (float)inb[((size_t)row << 10) + col];
                    const float nn  = fast_tanh(inv + r_ * hn);
                    const float htv = (float)A[(size_t)row * lda + col];  // ht (bf16, L2-hot)
                    outp[(size_t)row * 1040 + 16 + col] = (1.f - z_) * nn + z_ * htv;
                }
            }
        }
    }
}

// ---------------- readout: out[:, :16] ----------------
__global__ void k_ly(const float* __restrict__ outh, const float* __restrict__ state,
                     const float* __restrict__ Wly, const float* __restrict__ bly,
                     const int* __restrict__ y_type, float* __restrict__ outp, int B) {
    int t = blockIdx.x * 256 + threadIdx.x;
    if (t >= B * 16) return;
    int o = t & 15, b = t >> 4;
    const float4* hrow = (const float4*)(outh + (size_t)b * 1040 + 16);
    float s = bly[o];
#pragma unroll 4
    for (int k4 = 0; k4 < 256; ++k4) {
        float4 h = hrow[k4];
        int k = k4 << 2;
        s += h.x * Wly[(k + 0) * 16 + o] + h.y * Wly[(k + 1) * 16 + o]
           + h.z * Wly[(k + 2) * 16 + o] + h.w * Wly[(k + 3) * 16 + o];
    }
    outp[(size_t)b * 1040 + o] = (y_type[o] == 0) ? s : state[(size_t)b * 1040 + o];
}

// ---------------- launcher ----------------
extern "C" void kernel_launch(void* const* d_in, const int* in_sizes, int n_in,
                              void* d_out, int out_size, void* d_ws, size_t ws_size,
                              hipStream_t stream) {
    const float* state = (const float*)d_in[0];
    const float* xt    = (const float*)d_in[1];
    const float* W1    = (const float*)d_in[2];
    const float* b1    = (const float*)d_in[3];
    const float* W2    = (const float*)d_in[4];
    const float* b2    = (const float*)d_in[5];
    const float* Wih   = (const float*)d_in[6];
    const float* Whh   = (const float*)d_in[7];
    const float* bih   = (const float*)d_in[8];
    const float* bhh   = (const float*)d_in[9];
    const float* Wly   = (const float*)d_in[10];
    const float* bly   = (const float*)d_in[11];
    const int*   y_type = (const int*)d_in[12];
    float* out = (float*)d_out;

    const int B = in_sizes[0] / 1040;   // 32768

    char* ws = (char*)d_ws;
    fp8_t*  w1t8 = (fp8_t*) (ws);                    // 2048 x 1024 fp8
    fp8_t*  w2t8 = (fp8_t*) (ws + 2097152);          // 1024 x 2048 fp8
    bf16_t* wrz  = (bf16_t*)(ws + 4194304);          // 2048 x 1280 bf16
    bf16_t* win  = (bf16_t*)(ws + 9437184);          // 1024 x 256 bf16
    bf16_t* whn  = (bf16_t*)(ws + 9961472);          // 1024 x 1024 bf16
    float*  brz  = (float*) (ws + 12058624);         // 2048
    bf16_t* xh   = (bf16_t*)(ws + 12066816);         // B x 1280 bf16 [x|ht]
    fp8_t*  hs8  = (fp8_t*) (ws + 95952896);         // B x 1024 fp8 stage-h
    bf16_t* kacc = (bf16_t*)(ws + 129507328);        // B x 1024 bf16 k-sum
    fp8_t*  T8   = (fp8_t*) (ws + 196616192);        // B x 2048 fp8 tanh
    bf16_t* h0b  = (bf16_t*)(ws + 263725056);        // B x 1024 bf16 h0
    // overlays (after RK4 completes):
    bf16_t* rz   = (bf16_t*)(ws + 196616192);        // B x 2048 bf16 (over T8+h0b)
    bf16_t* inb  = (bf16_t*)(ws + 95952896);         // B x 1024 bf16 (over hs8+kacc)

    // weight prep + input casts
    k_cvt_transpose8<<<(1024 * 2048) / 256, 256, 0, stream>>>(W1, w1t8, 1024, 2048);
    k_cvt_transpose8<<<(2048 * 1024) / 256, 256, 0, stream>>>(W2, w2t8, 2048, 1024);
    k_build_wrz<<<(2048 * 1280) / 256, 256, 0, stream>>>(Wih, Whh, bih, bhh, wrz, brz);
    k_cvt_flat<<<(1024 * 256) / 256, 256, 0, stream>>>(Wih + 2048 * 256, win, 1024 * 256);
    k_cvt_flat<<<(1024 * 1024) / 256, 256, 0, stream>>>(Whh + 2048 * 1024, whn, 1024 * 1024);
    k_cvt_x<<<(B * 256) / 256, 256, 0, stream>>>(xt, xh, B);
    k_cvt_h0<<<(B * 1024) / 256, 256, 0, stream>>>(state, h0b, hs8, B);

    const int MB = B / 128;   // 256 m-tiles

    // ---- RK4 (fp8 BK=64 GEMMs: half the barrier windows) ----
    gemm128f8<EPI_TANH, 0><<<dim3(8, MB), 512, 0, stream>>>(hs8, 1024, w1t8, 2048, 1024,
        b1, T8, nullptr, nullptr, nullptr, nullptr);
    gemm128f8<EPI_RK4, 0><<<dim3(4, MB), 512, 0, stream>>>(T8, 2048, w2t8, 1024, 2048,
        b2, hs8, h0b, nullptr, kacc, nullptr);

    gemm128f8<EPI_TANH, 0><<<dim3(8, MB), 512, 0, stream>>>(hs8, 1024, w1t8, 2048, 1024,
        b1, T8, nullptr, nullptr, nullptr, nullptr);
    gemm128f8<EPI_RK4, 1><<<dim3(4, MB), 512, 0, stream>>>(T8, 2048, w2t8, 1024, 2048,
        b2, hs8, h0b, nullptr, kacc, nullptr);

    gemm128f8<EPI_TANH, 0><<<dim3(8, MB), 512, 0, stream>>>(hs8, 1024, w1t8, 2048, 1024,
        b1, T8, nullptr, nullptr, nullptr, nullptr);
    gemm128f8<EPI_RK4, 2><<<dim3(4, MB), 512, 0, stream>>>(T8, 2048, w2t8, 1024, 2048,
        b2, hs8, h0b, nullptr, kacc, nullptr);

    gemm128f8<EPI_TANH, 0><<<dim3(8, MB), 512, 0, stream>>>(hs8, 1024, w1t8, 2048, 1024,
        b1, T8, nullptr, nullptr, nullptr, nullptr);
    gemm128f8<EPI_RK4, 3><<<dim3(4, MB), 512, 0, stream>>>(T8, 2048, w2t8, 1024, 2048,
        b2, nullptr, nullptr, state, kacc, xh + 256);

    // ---- GRU (bf16 round-4 GEMMs) ----
    gemm128bf<EPI_SIG><<<dim3(8, MB), 512, 0, stream>>>(xh, 1280, wrz, 2048, 1280,
        brz, rz, nullptr, nullptr, nullptr);
    gemm128bf<EPI_BIASBF><<<dim3(4, MB), 512, 0, stream>>>(xh, 1280, win, 1024, 256,
        bih + 2048, inb, nullptr, nullptr, nullptr);
    gemm128bf<EPI_FIN><<<dim3(4, MB), 512, 0, stream>>>(xh + 256, 1280, whn, 1024, 1024,
        bhh + 2048, nullptr, rz, inb, out);

    // ---- readout out[:, :16] ----
    k_ly<<<(B * 16) / 256, 256, 0, stream>>>(out, state, Wly, bly, y_type, out, B);
}